// Round 5
// baseline (43.226 us; speedup 1.0000x reference)
//
#include <hip/hip_runtime.h>
#include <cfloat>

#define B_   32
#define H_   512
#define W_   512
#define HW_  (H_ * W_)
#define CHW_ (3 * HW_)
#define W4_  (W_ / 4)
#define HC_  32                 // h-chunks per image
#define ROWS_ (H_ / HC_)        // 16 rows per chunk
#define NP_   64                // s2 blocks / partials

__device__ __forceinline__ float max3f(float a, float b, float c) {
    return fmaxf(fmaxf(a, b), c);             // fuses to v_max3_f32
}
__device__ __forceinline__ float4 min4(float4 a, float4 b) {
    return make_float4(fminf(a.x, b.x), fminf(a.y, b.y), fminf(a.z, b.z), fminf(a.w, b.w));
}
__device__ __forceinline__ float4 max4(float4 a, float4 b) {
    return make_float4(fmaxf(a.x, b.x), fmaxf(a.y, b.y), fmaxf(a.z, b.z), fmaxf(a.w, b.w));
}
// clip+floor are monotone -> commute with min/max over H; applied in s2.
__device__ __forceinline__ float qclip(float m) {
    return floorf(fminf(fmaxf(m, 0.0f), 255.0f));
}

// Stage 1: ONE input per block (3 read streams/wave).
// grid = 2*B*HC = 2048 blocks x 128 threads (16 waves/CU).
__global__ __launch_bounds__(128) void s1_minmax(
        const float* __restrict__ pred, const float* __restrict__ tgt,
        float* __restrict__ ws, unsigned int* __restrict__ counter) {
    // reset the s2 ticket counter for this launch (s2 only runs after s1 completes)
    if (blockIdx.x == 0 && threadIdx.x == 0)
        __hip_atomic_store(counter, 0u, __ATOMIC_RELAXED, __HIP_MEMORY_SCOPE_AGENT);

    const int inp   = blockIdx.x & 1;
    const int bc    = blockIdx.x >> 1;            // 0..1023
    const int b     = bc >> 5;                    // / HC_
    const int chunk = bc & (HC_ - 1);
    const int w4    = threadIdx.x;                // 0..127

    const float4* S = reinterpret_cast<const float4*>(inp ? tgt : pred)
                      + (size_t)b * (CHW_ / 4);

    float4 mn = make_float4( FLT_MAX,  FLT_MAX,  FLT_MAX,  FLT_MAX);
    float4 mx = make_float4(-FLT_MAX, -FLT_MAX, -FLT_MAX, -FLT_MAX);

    const int h0 = chunk * ROWS_;
    #pragma unroll 8
    for (int h = h0; h < h0 + ROWS_; ++h) {
        const int base = h * W4_ + w4;
        float4 a  = S[base];
        float4 g  = S[base +      (HW_ / 4)];
        float4 c2 = S[base + 2 * (HW_ / 4)];
        float4 v = make_float4(max3f(a.x, g.x, c2.x), max3f(a.y, g.y, c2.y),
                               max3f(a.z, g.z, c2.z), max3f(a.w, g.w, c2.w));
        mn = min4(mn, v);
        mx = max4(mx, v);
    }

    // ws layout: 4 arrays of [B][HC][W] floats: minP, maxP, minT, maxT
    const size_t arr = (size_t)B_ * HC_ * W4_;    // float4 units
    const size_t o   = ((size_t)b * HC_ + chunk) * W4_ + w4;
    float4* wsv = reinterpret_cast<float4*>(ws);
    wsv[o + (size_t)(2 * inp + 0) * arr] = mn;    // minP / minT
    wsv[o + (size_t)(2 * inp + 1) * arr] = mx;    // maxP / maxT
}

// Stage 2 (fused): combine chunk partials per (b,w), clip+floor, squared diff,
// block tree-reduce; last finished block sums the 64 block-partials in fixed
// lane order (deterministic) and writes the scalar.
__global__ __launch_bounds__(256) void s2_reduce(
        const float* __restrict__ ws, double* __restrict__ partial,
        unsigned int* __restrict__ counter, float* __restrict__ out) {
    const int i = blockIdx.x * 256 + threadIdx.x;   // 0..16383
    const int b = i >> 9;
    const int w = i & (W_ - 1);

    const size_t arr = (size_t)B_ * HC_ * W_;
    const float* minP = ws;
    const float* maxP = ws + arr;
    const float* minT = ws + 2 * arr;
    const float* maxT = ws + 3 * arr;

    float mnP = FLT_MAX, mxP = -FLT_MAX, mnT = FLT_MAX, mxT = -FLT_MAX;
    #pragma unroll 4
    for (int c = 0; c < HC_; ++c) {
        const size_t o = ((size_t)b * HC_ + c) * W_ + w;
        mnP = fminf(mnP, minP[o]);
        mxP = fmaxf(mxP, maxP[o]);
        mnT = fminf(mnT, minT[o]);
        mxT = fmaxf(mxT, maxT[o]);
    }
    const float dmin = qclip(mnP) - qclip(mnT);
    const float dmax = qclip(mxP) - qclip(mxT);
    double s = (double)dmin * (double)dmin + (double)dmax * (double)dmax;

    __shared__ double sd[256];
    __shared__ int lastFlag;
    sd[threadIdx.x] = s;
    __syncthreads();
    #pragma unroll
    for (int st = 128; st > 0; st >>= 1) {
        if (threadIdx.x < st) sd[threadIdx.x] += sd[threadIdx.x + st];
        __syncthreads();
    }
    if (threadIdx.x == 0) {
        // publish this block's partial at device scope, then take a ticket
        __hip_atomic_store(&partial[blockIdx.x], sd[0],
                           __ATOMIC_RELEASE, __HIP_MEMORY_SCOPE_AGENT);
        unsigned int t = __hip_atomic_fetch_add(counter, 1u,
                           __ATOMIC_ACQ_REL, __HIP_MEMORY_SCOPE_AGENT);
        lastFlag = (t == NP_ - 1);
    }
    __syncthreads();

    // last block: wave 0 reads all 64 partials (device scope) and tree-sums
    // in fixed lane order -> bitwise deterministic.
    if (lastFlag && threadIdx.x < 64) {
        double v = __hip_atomic_load(&partial[threadIdx.x],
                                     __ATOMIC_ACQUIRE, __HIP_MEMORY_SCOPE_AGENT);
        #pragma unroll
        for (int st = 32; st > 0; st >>= 1) v += __shfl_down(v, st, 64);
        if (threadIdx.x == 0) out[0] = (float)(v / (double)(B_ * W_));
    }
}

extern "C" void kernel_launch(void* const* d_in, const int* in_sizes, int n_in,
                              void* d_out, int out_size, void* d_ws, size_t ws_size,
                              hipStream_t stream) {
    const float* pred = (const float*)d_in[0];
    const float* tgt  = (const float*)d_in[1];
    float* out = (float*)d_out;
    float* wsf = (float*)d_ws;

    // ws map: [4 * B * HC * W floats = 8.39 MB][64 doubles][1 uint]
    double* partial = (double*)(wsf + (size_t)4 * B_ * HC_ * W_);
    unsigned int* counter = (unsigned int*)(partial + NP_);

    hipLaunchKernelGGL(s1_minmax, dim3(2 * B_ * HC_), dim3(128), 0, stream,
                       pred, tgt, wsf, counter);
    hipLaunchKernelGGL(s2_reduce, dim3(NP_), dim3(256), 0, stream,
                       wsf, partial, counter, out);
}

// Round 6
// 40.149 us; speedup vs baseline: 1.0766x; 1.0766x over previous
//
#include <hip/hip_runtime.h>
#include <cfloat>

#define B_   32
#define H_   512
#define W_   512
#define HW_  (H_ * W_)
#define CHW_ (3 * HW_)
#define W4_  (W_ / 4)
#define HC_  16                 // h-chunks per image (R4 optimum)
#define ROWS_ (H_ / HC_)        // 32 rows per chunk
#define NP_   64                // s2 blocks / partials

__device__ __forceinline__ float max3f(float a, float b, float c) {
    return fmaxf(fmaxf(a, b), c);             // fuses to v_max3_f32
}
__device__ __forceinline__ float4 min4(float4 a, float4 b) {
    return make_float4(fminf(a.x, b.x), fminf(a.y, b.y), fminf(a.z, b.z), fminf(a.w, b.w));
}
__device__ __forceinline__ float4 max4(float4 a, float4 b) {
    return make_float4(fmaxf(a.x, b.x), fmaxf(a.y, b.y), fmaxf(a.z, b.z), fmaxf(a.w, b.w));
}
// clip+floor are monotone -> commute with min/max over H; applied in s2.
__device__ __forceinline__ float qclip(float m) {
    return floorf(fminf(fmaxf(m, 0.0f), 255.0f));
}

// Stage 1: ONE input per block (3 read streams/wave).
// grid = 2*B*HC = 1024 blocks x 128 threads  (R4-optimal: ~20% occupancy).
__global__ __launch_bounds__(128) void s1_minmax(
        const float* __restrict__ pred, const float* __restrict__ tgt,
        float* __restrict__ ws, unsigned int* __restrict__ counter) {
    // reset the s2 ticket counter for this launch (s2 runs only after s1 completes)
    if (blockIdx.x == 0 && threadIdx.x == 0)
        __hip_atomic_store(counter, 0u, __ATOMIC_RELAXED, __HIP_MEMORY_SCOPE_AGENT);

    const int inp   = blockIdx.x & 1;
    const int bc    = blockIdx.x >> 1;            // 0..511
    const int b     = bc >> 4;                    // / HC_
    const int chunk = bc & (HC_ - 1);
    const int w4    = threadIdx.x;                // 0..127

    const float4* S = reinterpret_cast<const float4*>(inp ? tgt : pred)
                      + (size_t)b * (CHW_ / 4);

    float4 mn = make_float4( FLT_MAX,  FLT_MAX,  FLT_MAX,  FLT_MAX);
    float4 mx = make_float4(-FLT_MAX, -FLT_MAX, -FLT_MAX, -FLT_MAX);

    const int h0 = chunk * ROWS_;
    #pragma unroll 8
    for (int h = h0; h < h0 + ROWS_; ++h) {
        const int base = h * W4_ + w4;
        float4 a  = S[base];
        float4 g  = S[base +      (HW_ / 4)];
        float4 c2 = S[base + 2 * (HW_ / 4)];
        float4 v = make_float4(max3f(a.x, g.x, c2.x), max3f(a.y, g.y, c2.y),
                               max3f(a.z, g.z, c2.z), max3f(a.w, g.w, c2.w));
        mn = min4(mn, v);
        mx = max4(mx, v);
    }

    // ws layout: 4 arrays of [B][HC][W] floats: minP, maxP, minT, maxT
    const size_t arr = (size_t)B_ * HC_ * W4_;    // float4 units
    const size_t o   = ((size_t)b * HC_ + chunk) * W4_ + w4;
    float4* wsv = reinterpret_cast<float4*>(ws);
    wsv[o + (size_t)(2 * inp + 0) * arr] = mn;    // minP / minT
    wsv[o + (size_t)(2 * inp + 1) * arr] = mx;    // maxP / maxT
}

// Stage 2 (fused): combine chunk partials per (b,w), clip+floor, squared diff,
// block tree-reduce; last finished block sums the 64 block-partials in fixed
// lane order (deterministic) and writes the scalar.
__global__ __launch_bounds__(256) void s2_reduce(
        const float* __restrict__ ws, double* __restrict__ partial,
        unsigned int* __restrict__ counter, float* __restrict__ out) {
    const int i = blockIdx.x * 256 + threadIdx.x;   // 0..16383
    const int b = i >> 9;
    const int w = i & (W_ - 1);

    const size_t arr = (size_t)B_ * HC_ * W_;
    const float* minP = ws;
    const float* maxP = ws + arr;
    const float* minT = ws + 2 * arr;
    const float* maxT = ws + 3 * arr;

    float mnP = FLT_MAX, mxP = -FLT_MAX, mnT = FLT_MAX, mxT = -FLT_MAX;
    #pragma unroll 4
    for (int c = 0; c < HC_; ++c) {
        const size_t o = ((size_t)b * HC_ + c) * W_ + w;
        mnP = fminf(mnP, minP[o]);
        mxP = fmaxf(mxP, maxP[o]);
        mnT = fminf(mnT, minT[o]);
        mxT = fmaxf(mxT, maxT[o]);
    }
    const float dmin = qclip(mnP) - qclip(mnT);
    const float dmax = qclip(mxP) - qclip(mxT);
    double s = (double)dmin * (double)dmin + (double)dmax * (double)dmax;

    __shared__ double sd[256];
    __shared__ int lastFlag;
    sd[threadIdx.x] = s;
    __syncthreads();
    #pragma unroll
    for (int st = 128; st > 0; st >>= 1) {
        if (threadIdx.x < st) sd[threadIdx.x] += sd[threadIdx.x + st];
        __syncthreads();
    }
    if (threadIdx.x == 0) {
        // publish this block's partial at device scope, then take a ticket
        __hip_atomic_store(&partial[blockIdx.x], sd[0],
                           __ATOMIC_RELEASE, __HIP_MEMORY_SCOPE_AGENT);
        unsigned int t = __hip_atomic_fetch_add(counter, 1u,
                           __ATOMIC_ACQ_REL, __HIP_MEMORY_SCOPE_AGENT);
        lastFlag = (t == NP_ - 1);
    }
    __syncthreads();

    // last block: wave 0 reads all 64 partials (device scope) and tree-sums
    // in fixed lane order -> bitwise deterministic.
    if (lastFlag && threadIdx.x < 64) {
        double v = __hip_atomic_load(&partial[threadIdx.x],
                                     __ATOMIC_ACQUIRE, __HIP_MEMORY_SCOPE_AGENT);
        #pragma unroll
        for (int st = 32; st > 0; st >>= 1) v += __shfl_down(v, st, 64);
        if (threadIdx.x == 0) out[0] = (float)(v / (double)(B_ * W_));
    }
}

extern "C" void kernel_launch(void* const* d_in, const int* in_sizes, int n_in,
                              void* d_out, int out_size, void* d_ws, size_t ws_size,
                              hipStream_t stream) {
    const float* pred = (const float*)d_in[0];
    const float* tgt  = (const float*)d_in[1];
    float* out = (float*)d_out;
    float* wsf = (float*)d_ws;

    // ws map: [4 * B * HC * W floats = 4.19 MB][64 doubles][1 uint]
    double* partial = (double*)(wsf + (size_t)4 * B_ * HC_ * W_);
    unsigned int* counter = (unsigned int*)(partial + NP_);

    hipLaunchKernelGGL(s1_minmax, dim3(2 * B_ * HC_), dim3(128), 0, stream,
                       pred, tgt, wsf, counter);
    hipLaunchKernelGGL(s2_reduce, dim3(NP_), dim3(256), 0, stream,
                       wsf, partial, counter, out);
}